// Round 15
// baseline (143.202 us; speedup 1.0000x reference)
//
#include <hip/hip_runtime.h>
#include <hip/hip_fp16.h>
#include <math.h>

#define HW 16384
#define Cc 256
#define CO 256

typedef unsigned short u16;
typedef unsigned int   u32;
typedef __attribute__((ext_vector_type(8))) _Float16 f16x8;
typedef __attribute__((ext_vector_type(4))) float f32x4;

__device__ __forceinline__ u16 f2h(float f) {
    return __half_as_ushort(__float2half(f));     // RNE f32->f16
}

// ---------------- Kernel 1: fused prep (main weight + offset weight frag order, fp16) ----------------
__global__ void k_prep(const float* __restrict__ w, const float* __restrict__ wof,
                       u16* __restrict__ wfr, u16* __restrict__ wofr) {
    int id = blockIdx.x * 256 + threadIdx.x;
    if (id < 589824) {
        int i    = id & 7;
        int lane = (id >> 3) & 63;
        int fb   = id >> 9;
        int k32  = fb % 72;
        int ot   = fb / 72;
        int o  = ot * 16 + (lane & 15);
        int K  = k32 * 32 + (lane >> 4) * 8 + i;
        int kt = K >> 8;
        int c  = K & 255;
        wfr[id] = f2h(w[((size_t)o * 256 + c) * 9 + kt]);
    } else if (id < 663552) {
        int id2  = id - 589824;
        int i    = id2 & 7;
        int lane = (id2 >> 3) & 63;
        int fb   = id2 >> 9;
        int k32  = fb % 72;
        int mt   = fb / 72;
        int o  = mt * 16 + (lane & 15);
        int K  = k32 * 32 + (lane >> 4) * 8 + i;
        int t  = K >> 8;
        int c  = K & 255;
        float v = (o < 27) ? wof[((size_t)o * 256 + c) * 9 + t] : 0.0f;
        wofr[id2] = f2h(v);
    }
}

// ---------------- Kernel 1e: x -> Xt[b][hw][c] fp16 ----------------
__global__ __launch_bounds__(256) void k_xt(const float* __restrict__ x, u16* __restrict__ Xt) {
    const int tid = threadIdx.x;
    const int bid = blockIdx.x;              // 512 = b*256 + hwblk
    const int hw0 = (bid & 255) * 64;
    const int b   = bid >> 8;
    const int hwl = tid & 63;
    const int cg  = tid >> 6;
    const int hw  = hw0 + hwl;
    const float* xb = x + ((size_t)b << 22);
    u16* dst = Xt + (((size_t)b << 14) + hw) * 256 + cg * 64;
    #pragma unroll
    for (int oct = 0; oct < 8; ++oct) {
        int c0 = cg * 64 + oct * 8;
        u32 pk[4];
        #pragma unroll
        for (int q = 0; q < 4; ++q) {
            float v0 = xb[((size_t)(c0 + 2 * q) << 14) + hw];
            float v1 = xb[((size_t)(c0 + 2 * q + 1) << 14) + hw];
            pk[q] = (u32)f2h(v0) | ((u32)f2h(v1) << 16);
        }
        *(uint4*)(dst + oct * 8) = make_uint4(pk[0], pk[1], pk[2], pk[3]);
    }
}

// ---------------- Kernel 2: offset conv MFMA (fp16), FULL K per block (no atomics) ----------------
__global__ __launch_bounds__(256) void k_offmfma(const u16* __restrict__ Xt,
                                                 const u16* __restrict__ wofr,
                                                 const float* __restrict__ bof,
                                                 float* __restrict__ om) {
    const int tid  = threadIdx.x;
    const int wid  = tid >> 6;
    const int lane = tid & 63;
    const int bid  = blockIdx.x;
    const int wq   = bid & 1;
    const int h    = (bid >> 1) & 127;
    const int b    = bid >> 8;

    const int lr = lane & 15;
    const int lg = lane >> 4;
    const int w  = wq * 64 + wid * 16 + lr;

    f32x4 acc0 = (f32x4)0.0f, acc1 = (f32x4)0.0f;
    const u16* XtB = Xt + (((size_t)b << 14) << 8);

    for (int t = 0; t < 9; ++t) {
        int dh = t / 3 - 1;
        int dw = t % 3 - 1;
        int hh = h + dh;
        int ww = w + dw;
        bool valid = (hh >= 0) && (hh < 128) && (ww >= 0) && (ww < 128);
        int hc = min(max(hh, 0), 127);
        int wc = min(max(ww, 0), 127);
        const u16* xrow = XtB + ((size_t)(hc * 128 + wc) << 8) + lg * 8;
        #pragma unroll
        for (int c32 = 0; c32 < 8; ++c32) {
            int k32 = t * 8 + c32;
            f16x8 bv = *(const f16x8*)(xrow + c32 * 32);
            if (!valid) bv = (f16x8)0;
            f16x8 a0 = *(const f16x8*)(wofr + (((size_t)k32 * 64 + lane) << 3));
            f16x8 a1 = *(const f16x8*)(wofr + ((((size_t)(72 + k32)) * 64 + lane) << 3));
            acc0 = __builtin_amdgcn_mfma_f32_16x16x32_f16(a0, bv, acc0, 0, 0, 0);
            acc1 = __builtin_amdgcn_mfma_f32_16x16x32_f16(a1, bv, acc1, 0, 0, 0);
        }
    }

    float* omb = om + ((size_t)b * 27 << 14) + h * 128 + w;
    #pragma unroll
    for (int j = 0; j < 4; ++j) {
        int o = lg * 4 + j;
        omb[(size_t)o << 14] = acc0[j] + bof[o];
        int o1 = 16 + lg * 4 + j;
        if (o1 < 27) omb[(size_t)o1 << 14] = acc1[j] + bof[o1];
    }
}

// ---------------- Kernel 3: FUSED deform-gather + fp16 MFMA GEMM, 8 waves ----------------
// r14 schedule (65us) + micro-cuts: ping-pong af/afn (kills 16 movs/step),
// pre-shifted byte corner offsets, setprio around MFMA, fp16 y output.
__global__ __launch_bounds__(512) void k_sgemm(const u16* __restrict__ Xt,
                                               const float* __restrict__ om,
                                               const u16* __restrict__ wfr,
                                               const float* __restrict__ bias,
                                               u16* __restrict__ y,
                                               float* __restrict__ psum) {
    __shared__ int4    soff[9][64];           // corner BYTE offsets (hw*512)
    __shared__ __half2 swt2[9][64][4];
    __shared__ __align__(16) u16 Blds[2][4096];

    const int tid  = threadIdx.x;            // 0..511
    const int wid  = tid >> 6;                // 0..7
    const int lane = tid & 63;
    const int bid  = ((blockIdx.x & 7) << 6) | (blockIdx.x >> 3);  // XCD swizzle
    const int p0   = bid * 64;
    const int b    = p0 >> 14;
    const int hwb  = p0 & 16383;

    // ---- coords: 64 pos x 9 taps ----
    for (int e = tid; e < 576; e += 512) {
        int t = e >> 6, j = e & 63;
        int hw = hwb + j;
        int h = hw >> 7, wc = hw & 127;
        const size_t ob = (size_t)b * 27 * HW;
        float oy = om[ob + (size_t)t * HW + hw];
        float ox = om[ob + (size_t)(9 + t) * HW + hw];
        float mv = om[ob + (size_t)(18 + t) * HW + hw];
        mv = 1.0f / (1.0f + expf(-mv));
        float py = (float)h - 1.0f + (float)(t / 3) + oy;
        float px = (float)wc - 1.0f + (float)(t % 3) + ox;
        float y0f = floorf(py), x0f = floorf(px);
        float wy = py - y0f, wx = px - x0f;
        int iy = (int)y0f, ix = (int)x0f;
        float w4[4] = {(1.0f - wy) * (1.0f - wx), (1.0f - wy) * wx,
                       wy * (1.0f - wx),          wy * wx};
        const int dy[4] = {0, 0, 1, 1};
        const int dx[4] = {0, 1, 0, 1};
        int of[4];
        #pragma unroll
        for (int r = 0; r < 4; ++r) {
            int yy = iy + dy[r], xx = ix + dx[r];
            bool v = (yy >= 0) && (yy <= 127) && (xx >= 0) && (xx <= 127);
            int yc = min(max(yy, 0), 127);
            int xc = min(max(xx, 0), 127);
            of[r] = (yc * 128 + xc) << 9;       // byte offset into Xt batch plane
            swt2[t][j][r] = __float2half2_rn(v ? w4[r] * mv : 0.0f);
        }
        soff[t][j] = make_int4(of[0], of[1], of[2], of[3]);
    }
    __syncthreads();

    const int jp    = tid >> 3;                          // pos row 0..63
    const int kbyte = (((tid & 7) ^ (jp & 7)) << 4);     // pre-swizzled 8-ch slice (bytes)
    const char* XtC = (const char*)(Xt + (((size_t)b << 14) << 8));

    const int lg = lane >> 4;
    const int lr = lane & 15;

    f32x4 acc[2][4];
    #pragma unroll
    for (int m = 0; m < 2; ++m)
        #pragma unroll
        for (int n = 0; n < 4; ++n) acc[m][n] = (f32x4)0.0f;

    auto gload = [&](int s, uint4* gg) {
        int cb = ((s & 3) << 7) + kbyte;
        int4 oa = soff[s >> 2][jp];
        gg[0] = *(const uint4*)(XtC + (u32)(oa.x + cb));
        gg[1] = *(const uint4*)(XtC + (u32)(oa.y + cb));
        gg[2] = *(const uint4*)(XtC + (u32)(oa.z + cb));
        gg[3] = *(const uint4*)(XtC + (u32)(oa.w + cb));
    };
    auto gcomb = [&](int s, const uint4* gg, int buf) {
        int t = s >> 2;
        __half2 w0 = swt2[t][jp][0];
        __half2 w1 = swt2[t][jp][1];
        __half2 w2 = swt2[t][jp][2];
        __half2 w3 = swt2[t][jp][3];
        const __half2* c0 = (const __half2*)&gg[0];
        const __half2* c1 = (const __half2*)&gg[1];
        const __half2* c2 = (const __half2*)&gg[2];
        const __half2* c3 = (const __half2*)&gg[3];
        u32 o4[4];
        #pragma unroll
        for (int q = 0; q < 4; ++q) {
            __half2 o = __hmul2(c0[q], w0);
            o = __hfma2(c1[q], w1, o);
            o = __hfma2(c2[q], w2, o);
            o = __hfma2(c3[q], w3, o);
            o4[q] = *(const u32*)&o;
        }
        *(uint4*)((char*)&Blds[buf][0] + tid * 16) = make_uint4(o4[0], o4[1], o4[2], o4[3]);
    };
    auto aload = [&](int k32g, f16x8 dst2[2][2]) {
        #pragma unroll
        for (int kk = 0; kk < 2; ++kk)
            #pragma unroll
            for (int m = 0; m < 2; ++m)
                dst2[kk][m] = *(const f16x8*)(wfr +
                    ((size_t)((wid * 2 + m) * 72 + k32g + kk) << 9) + (size_t)lane * 8);
    };
    auto domfma = [&](int cur, f16x8 afv[2][2]) {
        const char* bb2 = (const char*)&Blds[cur][0];
        __builtin_amdgcn_s_setprio(1);
        #pragma unroll
        for (int kk = 0; kk < 2; ++kk) {
            f16x8 bfv[4];
            #pragma unroll
            for (int n = 0; n < 4; ++n) {
                int row  = n * 16 + lr;
                int boff = row * 128 + ((kk * 64 + lg * 16) ^ ((row & 7) << 4));
                bfv[n] = *(const f16x8*)(bb2 + boff);
            }
            #pragma unroll
            for (int m = 0; m < 2; ++m)
                #pragma unroll
                for (int n = 0; n < 4; ++n)
                    acc[m][n] = __builtin_amdgcn_mfma_f32_16x16x32_f16(afv[kk][m], bfv[n], acc[m][n], 0, 0, 0);
        }
        __builtin_amdgcn_s_setprio(0);
    };

    f16x8 afA[2][2], afB[2][2];
    // ---- prologue: step 0 ----
    {
        uint4 g[4];
        gload(0, g);
        aload(0, afA);
        gcomb(0, g, 0);
    }
    __syncthreads();

    int cur = 0;
    #pragma unroll 1
    for (int sp = 0; sp < 18; ++sp) {
        const int s0 = 2 * sp;          // even step: consume afA, load afB
        const int s1 = s0 + 1;          // odd step:  consume afB, load afA
        {
            uint4 gn[4];
            gload(s0 + 1, gn);          // s0 <= 34 always
            aload(2 * (s0 + 1), afB);
            domfma(cur, afA);
            gcomb(s0 + 1, gn, cur ^ 1);
            __syncthreads();
            cur ^= 1;
        }
        {
            uint4 gn[4];
            if (s1 < 35) {
                gload(s1 + 1, gn);
                aload(2 * (s1 + 1), afA);
            }
            domfma(cur, afB);
            if (s1 < 35) {
                gcomb(s1 + 1, gn, cur ^ 1);
            }
            __syncthreads();
            cur ^= 1;
        }
    }

    // ---- epilogue: bias + write y (fp16) + fused BN partial sums (spread 32-way) ----
    const int hw0  = hwb + lr;
    const int slot = (bid & 31) << 9;          // 32 psum copies of 512 floats
    #pragma unroll
    for (int m = 0; m < 2; ++m) {
        #pragma unroll
        for (int jj = 0; jj < 4; ++jj) {
            int o = wid * 32 + m * 16 + lg * 4 + jj;
            float bv = bias[o];
            u16* ya = y + ((size_t)b * 256 + o) * HW + hw0;
            float ssum = 0.0f, ssq = 0.0f;
            #pragma unroll
            for (int n = 0; n < 4; ++n) {
                float v = acc[m][n][jj] + bv;
                ya[n * 16] = f2h(v);
                ssum += v;
                ssq  += v * v;
            }
            #pragma unroll
            for (int d = 1; d < 16; d <<= 1) {
                ssum += __shfl_xor(ssum, d);
                ssq  += __shfl_xor(ssq, d);
            }
            if (lr == 0) {
                atomicAdd(&psum[slot + o], ssum);
                atomicAdd(&psum[slot + 256 + o], ssq);
            }
        }
    }
}

// ---------------- Kernel 4: psum (32 copies) -> mu / rsig ----------------
__global__ void k_stats2(const float* __restrict__ psum, float* __restrict__ st) {
    int o = threadIdx.x;
    float s = 0.0f, q = 0.0f;
    #pragma unroll 8
    for (int r = 0; r < 32; ++r) {
        s += psum[(r << 9) + o];
        q += psum[(r << 9) + 256 + o];
    }
    float mu  = s / 32768.0f;
    float var = q / 32768.0f - mu * mu;
    st[o]       = mu;
    st[256 + o] = rsqrtf(var + 1e-5f);
}

// ---------------- Kernel 5: normalize + relu (fp16 y input) ----------------
__global__ void k_norm(const u16* __restrict__ y, const float* __restrict__ stats,
                       const float* __restrict__ gamma, const float* __restrict__ beta,
                       float* __restrict__ out) {
    int i8 = blockIdx.x * 256 + threadIdx.x;       // uint4 index = 8 fp16 elems
    if (i8 >= (2 * CO * HW) / 8) return;
    int o = ((i8 * 8) >> 14) & 255;
    float g  = gamma[o] * stats[256 + o];
    float bt = beta[o] - stats[o] * g;
    uint4 v = ((const uint4*)y)[i8];
    const __half2* h2 = (const __half2*)&v;
    float4 r0, r1;
    float2 f0 = __half22float2(h2[0]);
    float2 f1 = __half22float2(h2[1]);
    float2 f2 = __half22float2(h2[2]);
    float2 f3 = __half22float2(h2[3]);
    r0.x = fmaxf(fmaf(f0.x, g, bt), 0.0f);
    r0.y = fmaxf(fmaf(f0.y, g, bt), 0.0f);
    r0.z = fmaxf(fmaf(f1.x, g, bt), 0.0f);
    r0.w = fmaxf(fmaf(f1.y, g, bt), 0.0f);
    r1.x = fmaxf(fmaf(f2.x, g, bt), 0.0f);
    r1.y = fmaxf(fmaf(f2.y, g, bt), 0.0f);
    r1.z = fmaxf(fmaf(f3.x, g, bt), 0.0f);
    r1.w = fmaxf(fmaf(f3.y, g, bt), 0.0f);
    float4* op = (float4*)(out + (size_t)i8 * 8);
    op[0] = r0;
    op[1] = r1;
}

extern "C" void kernel_launch(void* const* d_in, const int* in_sizes, int n_in,
                              void* d_out, int out_size, void* d_ws, size_t ws_size,
                              hipStream_t stream) {
    const float* x      = (const float*)d_in[0];
    const float* w_off  = (const float*)d_in[1];
    const float* b_off  = (const float*)d_in[2];
    const float* weight = (const float*)d_in[3];
    const float* bias   = (const float*)d_in[4];
    const float* gamma  = (const float*)d_in[5];
    const float* beta   = (const float*)d_in[6];
    float* out = (float*)d_out;

    float* ws   = (float*)d_ws;
    float* om   = ws;                        // 884736 f
    float* st   = om + 884736;               // 512 f
    float* ps   = st + 512;                  // 16384 f (32 copies x 512)
    u16*   yb   = (u16*)(ps + 16384);        // 8388608 u16 (16.8 MB)
    u16*   wfr  = yb + 8388608;              // 589824 u16
    u16*   wofr = wfr + 589824;              // 73728 u16
    u16*   Xt   = wofr + 73728;              // 8388608 u16 (16.8 MB)

    k_prep<<<2592, 256, 0, stream>>>(weight, w_off, wfr, wofr);
    k_xt<<<512, 256, 0, stream>>>(x, Xt);
    hipMemsetAsync(ps, 0, 16384 * sizeof(float), stream);
    k_offmfma<<<512, 256, 0, stream>>>(Xt, wofr, b_off, om);

    k_sgemm<<<512, 512, 0, stream>>>(Xt, om, wfr, bias, yb, ps);

    k_stats2<<<1, 256, 0, stream>>>(ps, st);
    k_norm<<<(2 * CO * HW / 8 + 255) / 256, 256, 0, stream>>>(yb, st, gamma, beta, out);
}

// Round 16
// 123.397 us; speedup vs baseline: 1.1605x; 1.1605x over previous
//
#include <hip/hip_runtime.h>
#include <hip/hip_fp16.h>
#include <math.h>

#define HW 16384
#define Cc 256
#define CO 256

typedef unsigned short u16;
typedef unsigned int   u32;
typedef __attribute__((ext_vector_type(8))) _Float16 f16x8;
typedef __attribute__((ext_vector_type(4))) float f32x4;

__device__ __forceinline__ u16 f2h(float f) {
    return __half_as_ushort(__float2half(f));     // RNE f32->f16
}

// ---------------- Kernel 1: fused prep (main weight + offset weight frag order, fp16) ----------------
__global__ void k_prep(const float* __restrict__ w, const float* __restrict__ wof,
                       u16* __restrict__ wfr, u16* __restrict__ wofr) {
    int id = blockIdx.x * 256 + threadIdx.x;
    if (id < 589824) {
        int i    = id & 7;
        int lane = (id >> 3) & 63;
        int fb   = id >> 9;
        int k32  = fb % 72;
        int ot   = fb / 72;
        int o  = ot * 16 + (lane & 15);
        int K  = k32 * 32 + (lane >> 4) * 8 + i;
        int kt = K >> 8;
        int c  = K & 255;
        wfr[id] = f2h(w[((size_t)o * 256 + c) * 9 + kt]);
    } else if (id < 663552) {
        int id2  = id - 589824;
        int i    = id2 & 7;
        int lane = (id2 >> 3) & 63;
        int fb   = id2 >> 9;
        int k32  = fb % 72;
        int mt   = fb / 72;
        int o  = mt * 16 + (lane & 15);
        int K  = k32 * 32 + (lane >> 4) * 8 + i;
        int t  = K >> 8;
        int c  = K & 255;
        float v = (o < 27) ? wof[((size_t)o * 256 + c) * 9 + t] : 0.0f;
        wofr[id2] = f2h(v);
    }
}

// ---------------- Kernel 1e: x -> Xt[b][hw][c] fp16 ----------------
__global__ __launch_bounds__(256) void k_xt(const float* __restrict__ x, u16* __restrict__ Xt) {
    const int tid = threadIdx.x;
    const int bid = blockIdx.x;              // 512 = b*256 + hwblk
    const int hw0 = (bid & 255) * 64;
    const int b   = bid >> 8;
    const int hwl = tid & 63;
    const int cg  = tid >> 6;
    const int hw  = hw0 + hwl;
    const float* xb = x + ((size_t)b << 22);
    u16* dst = Xt + (((size_t)b << 14) + hw) * 256 + cg * 64;
    #pragma unroll
    for (int oct = 0; oct < 8; ++oct) {
        int c0 = cg * 64 + oct * 8;
        u32 pk[4];
        #pragma unroll
        for (int q = 0; q < 4; ++q) {
            float v0 = xb[((size_t)(c0 + 2 * q) << 14) + hw];
            float v1 = xb[((size_t)(c0 + 2 * q + 1) << 14) + hw];
            pk[q] = (u32)f2h(v0) | ((u32)f2h(v1) << 16);
        }
        *(uint4*)(dst + oct * 8) = make_uint4(pk[0], pk[1], pk[2], pk[3]);
    }
}

// ---------------- Kernel 2: offset conv MFMA (fp16), FULL K per block (no atomics) ----------------
__global__ __launch_bounds__(256) void k_offmfma(const u16* __restrict__ Xt,
                                                 const u16* __restrict__ wofr,
                                                 const float* __restrict__ bof,
                                                 float* __restrict__ om) {
    const int tid  = threadIdx.x;
    const int wid  = tid >> 6;
    const int lane = tid & 63;
    const int bid  = blockIdx.x;
    const int wq   = bid & 1;
    const int h    = (bid >> 1) & 127;
    const int b    = bid >> 8;

    const int lr = lane & 15;
    const int lg = lane >> 4;
    const int w  = wq * 64 + wid * 16 + lr;

    f32x4 acc0 = (f32x4)0.0f, acc1 = (f32x4)0.0f;
    const u16* XtB = Xt + (((size_t)b << 14) << 8);

    for (int t = 0; t < 9; ++t) {
        int dh = t / 3 - 1;
        int dw = t % 3 - 1;
        int hh = h + dh;
        int ww = w + dw;
        bool valid = (hh >= 0) && (hh < 128) && (ww >= 0) && (ww < 128);
        int hc = min(max(hh, 0), 127);
        int wc = min(max(ww, 0), 127);
        const u16* xrow = XtB + ((size_t)(hc * 128 + wc) << 8) + lg * 8;
        #pragma unroll
        for (int c32 = 0; c32 < 8; ++c32) {
            int k32 = t * 8 + c32;
            f16x8 bv = *(const f16x8*)(xrow + c32 * 32);
            if (!valid) bv = (f16x8)0;
            f16x8 a0 = *(const f16x8*)(wofr + (((size_t)k32 * 64 + lane) << 3));
            f16x8 a1 = *(const f16x8*)(wofr + ((((size_t)(72 + k32)) * 64 + lane) << 3));
            acc0 = __builtin_amdgcn_mfma_f32_16x16x32_f16(a0, bv, acc0, 0, 0, 0);
            acc1 = __builtin_amdgcn_mfma_f32_16x16x32_f16(a1, bv, acc1, 0, 0, 0);
        }
    }

    float* omb = om + ((size_t)b * 27 << 14) + h * 128 + w;
    #pragma unroll
    for (int j = 0; j < 4; ++j) {
        int o = lg * 4 + j;
        omb[(size_t)o << 14] = acc0[j] + bof[o];
        int o1 = 16 + lg * 4 + j;
        if (o1 < 27) omb[(size_t)o1 << 14] = acc1[j] + bof[o1];
    }
}

// ---------------- Kernel 3: FUSED deform-gather + fp16 MFMA GEMM, 8 waves ----------------
// EXACT r14 main loop (65us): grid 512 (XCD-swizzled), block 512 = 8 waves,
// M=32/wave, N=64 pos, K=2304, 36 steps, single-step prefetch, af/afn copy.
// ONLY delta vs r14: y stored fp16 (epilogue-only; halves k_sgemm write +
// k_norm read traffic).
__global__ __launch_bounds__(512) void k_sgemm(const u16* __restrict__ Xt,
                                               const float* __restrict__ om,
                                               const u16* __restrict__ wfr,
                                               const float* __restrict__ bias,
                                               u16* __restrict__ y,
                                               float* __restrict__ psum) {
    __shared__ int4    soff[9][64];
    __shared__ __half2 swt2[9][64][4];
    __shared__ __align__(16) u16 Blds[2][4096];

    const int tid  = threadIdx.x;            // 0..511
    const int wid  = tid >> 6;                // 0..7
    const int lane = tid & 63;
    const int bid  = ((blockIdx.x & 7) << 6) | (blockIdx.x >> 3);  // XCD swizzle
    const int p0   = bid * 64;
    const int b    = p0 >> 14;
    const int hwb  = p0 & 16383;

    // ---- coords: 64 pos x 9 taps ----
    for (int e = tid; e < 576; e += 512) {
        int t = e >> 6, j = e & 63;
        int hw = hwb + j;
        int h = hw >> 7, wc = hw & 127;
        const size_t ob = (size_t)b * 27 * HW;
        float oy = om[ob + (size_t)t * HW + hw];
        float ox = om[ob + (size_t)(9 + t) * HW + hw];
        float mv = om[ob + (size_t)(18 + t) * HW + hw];
        mv = 1.0f / (1.0f + expf(-mv));
        float py = (float)h - 1.0f + (float)(t / 3) + oy;
        float px = (float)wc - 1.0f + (float)(t % 3) + ox;
        float y0f = floorf(py), x0f = floorf(px);
        float wy = py - y0f, wx = px - x0f;
        int iy = (int)y0f, ix = (int)x0f;
        float w4[4] = {(1.0f - wy) * (1.0f - wx), (1.0f - wy) * wx,
                       wy * (1.0f - wx),          wy * wx};
        const int dy[4] = {0, 0, 1, 1};
        const int dx[4] = {0, 1, 0, 1};
        int of[4];
        #pragma unroll
        for (int r = 0; r < 4; ++r) {
            int yy = iy + dy[r], xx = ix + dx[r];
            bool v = (yy >= 0) && (yy <= 127) && (xx >= 0) && (xx <= 127);
            int yc = min(max(yy, 0), 127);
            int xc = min(max(xx, 0), 127);
            of[r] = yc * 128 + xc;
            swt2[t][j][r] = __float2half2_rn(v ? w4[r] * mv : 0.0f);
        }
        soff[t][j] = make_int4(of[0], of[1], of[2], of[3]);
    }
    __syncthreads();

    const int jp    = tid >> 3;                        // pos row 0..63
    const int kloc8 = (((tid & 7) ^ (jp & 7)) << 3);   // pre-swizzled 8-ch k-slice
    const u16* XtB  = Xt + (((size_t)b << 14) << 8);

    const int lg = lane >> 4;
    const int lr = lane & 15;

    f32x4 acc[2][4];
    #pragma unroll
    for (int m = 0; m < 2; ++m)
        #pragma unroll
        for (int n = 0; n < 4; ++n) acc[m][n] = (f32x4)0.0f;

    auto gload = [&](int s, uint4* gg) {
        int t = s >> 2;
        int c = ((s & 3) << 6) + kloc8;
        int4 oa = soff[t][jp];
        gg[0] = *(const uint4*)(XtB + (size_t)oa.x * 256 + c);
        gg[1] = *(const uint4*)(XtB + (size_t)oa.y * 256 + c);
        gg[2] = *(const uint4*)(XtB + (size_t)oa.z * 256 + c);
        gg[3] = *(const uint4*)(XtB + (size_t)oa.w * 256 + c);
    };
    auto gcomb = [&](int s, const uint4* gg, int buf) {
        int t = s >> 2;
        __half2 w0 = swt2[t][jp][0];
        __half2 w1 = swt2[t][jp][1];
        __half2 w2 = swt2[t][jp][2];
        __half2 w3 = swt2[t][jp][3];
        const __half2* c0 = (const __half2*)&gg[0];
        const __half2* c1 = (const __half2*)&gg[1];
        const __half2* c2 = (const __half2*)&gg[2];
        const __half2* c3 = (const __half2*)&gg[3];
        u32 o4[4];
        #pragma unroll
        for (int q = 0; q < 4; ++q) {
            __half2 o = __hmul2(c0[q], w0);
            o = __hfma2(c1[q], w1, o);
            o = __hfma2(c2[q], w2, o);
            o = __hfma2(c3[q], w3, o);
            o4[q] = *(const u32*)&o;
        }
        *(uint4*)((char*)&Blds[buf][0] + tid * 16) = make_uint4(o4[0], o4[1], o4[2], o4[3]);
    };
    auto aload = [&](int k32g, f16x8 dst2[2][2]) {
        #pragma unroll
        for (int kk = 0; kk < 2; ++kk)
            #pragma unroll
            for (int m = 0; m < 2; ++m)
                dst2[kk][m] = *(const f16x8*)(wfr +
                    ((size_t)((wid * 2 + m) * 72 + k32g + kk) << 9) + (size_t)lane * 8);
    };

    f16x8 af[2][2];
    // ---- prologue: step 0 ----
    {
        uint4 g[4];
        gload(0, g);
        aload(0, af);
        gcomb(0, g, 0);
    }
    __syncthreads();

    int cur = 0;
    for (int s = 0; s < 36; ++s) {
        const int nxt = cur ^ 1;
        uint4 gn[4];
        f16x8 afn[2][2];
        if (s < 35) {
            gload(s + 1, gn);
            aload(2 * (s + 1), afn);
        }

        const char* bb2 = (const char*)&Blds[cur][0];
        #pragma unroll
        for (int kk = 0; kk < 2; ++kk) {
            f16x8 bfv[4];
            #pragma unroll
            for (int n = 0; n < 4; ++n) {
                int row  = n * 16 + lr;
                int boff = row * 128 + ((kk * 64 + lg * 16) ^ ((row & 7) << 4));
                bfv[n] = *(const f16x8*)(bb2 + boff);
            }
            #pragma unroll
            for (int m = 0; m < 2; ++m)
                #pragma unroll
                for (int n = 0; n < 4; ++n)
                    acc[m][n] = __builtin_amdgcn_mfma_f32_16x16x32_f16(af[kk][m], bfv[n], acc[m][n], 0, 0, 0);
        }

        if (s < 35) {
            gcomb(s + 1, gn, nxt);
            #pragma unroll
            for (int kk = 0; kk < 2; ++kk)
                #pragma unroll
                for (int m = 0; m < 2; ++m)
                    af[kk][m] = afn[kk][m];
        }
        __syncthreads();
        cur = nxt;
    }

    // ---- epilogue: bias + write y (fp16) + fused BN partial sums (spread 32-way) ----
    const int hw0  = hwb + lr;
    const int slot = (bid & 31) << 9;          // 32 psum copies of 512 floats
    #pragma unroll
    for (int m = 0; m < 2; ++m) {
        #pragma unroll
        for (int jj = 0; jj < 4; ++jj) {
            int o = wid * 32 + m * 16 + lg * 4 + jj;
            float bv = bias[o];
            u16* ya = y + ((size_t)b * 256 + o) * HW + hw0;
            float ssum = 0.0f, ssq = 0.0f;
            #pragma unroll
            for (int n = 0; n < 4; ++n) {
                float v = acc[m][n][jj] + bv;
                ya[n * 16] = f2h(v);
                ssum += v;
                ssq  += v * v;
            }
            #pragma unroll
            for (int d = 1; d < 16; d <<= 1) {
                ssum += __shfl_xor(ssum, d);
                ssq  += __shfl_xor(ssq, d);
            }
            if (lr == 0) {
                atomicAdd(&psum[slot + o], ssum);
                atomicAdd(&psum[slot + 256 + o], ssq);
            }
        }
    }
}

// ---------------- Kernel 4: psum (32 copies) -> mu / rsig ----------------
__global__ void k_stats2(const float* __restrict__ psum, float* __restrict__ st) {
    int o = threadIdx.x;
    float s = 0.0f, q = 0.0f;
    #pragma unroll 8
    for (int r = 0; r < 32; ++r) {
        s += psum[(r << 9) + o];
        q += psum[(r << 9) + 256 + o];
    }
    float mu  = s / 32768.0f;
    float var = q / 32768.0f - mu * mu;
    st[o]       = mu;
    st[256 + o] = rsqrtf(var + 1e-5f);
}

// ---------------- Kernel 5: normalize + relu (fp16 y input) ----------------
__global__ void k_norm(const u16* __restrict__ y, const float* __restrict__ stats,
                       const float* __restrict__ gamma, const float* __restrict__ beta,
                       float* __restrict__ out) {
    int i8 = blockIdx.x * 256 + threadIdx.x;       // uint4 index = 8 fp16 elems
    if (i8 >= (2 * CO * HW) / 8) return;
    int o = ((i8 * 8) >> 14) & 255;
    float g  = gamma[o] * stats[256 + o];
    float bt = beta[o] - stats[o] * g;
    uint4 v = ((const uint4*)y)[i8];
    const __half2* h2 = (const __half2*)&v;
    float4 r0, r1;
    float2 f0 = __half22float2(h2[0]);
    float2 f1 = __half22float2(h2[1]);
    float2 f2 = __half22float2(h2[2]);
    float2 f3 = __half22float2(h2[3]);
    r0.x = fmaxf(fmaf(f0.x, g, bt), 0.0f);
    r0.y = fmaxf(fmaf(f0.y, g, bt), 0.0f);
    r0.z = fmaxf(fmaf(f1.x, g, bt), 0.0f);
    r0.w = fmaxf(fmaf(f1.y, g, bt), 0.0f);
    r1.x = fmaxf(fmaf(f2.x, g, bt), 0.0f);
    r1.y = fmaxf(fmaf(f2.y, g, bt), 0.0f);
    r1.z = fmaxf(fmaf(f3.x, g, bt), 0.0f);
    r1.w = fmaxf(fmaf(f3.y, g, bt), 0.0f);
    float4* op = (float4*)(out + (size_t)i8 * 8);
    op[0] = r0;
    op[1] = r1;
}

extern "C" void kernel_launch(void* const* d_in, const int* in_sizes, int n_in,
                              void* d_out, int out_size, void* d_ws, size_t ws_size,
                              hipStream_t stream) {
    const float* x      = (const float*)d_in[0];
    const float* w_off  = (const float*)d_in[1];
    const float* b_off  = (const float*)d_in[2];
    const float* weight = (const float*)d_in[3];
    const float* bias   = (const float*)d_in[4];
    const float* gamma  = (const float*)d_in[5];
    const float* beta   = (const float*)d_in[6];
    float* out = (float*)d_out;

    float* ws   = (float*)d_ws;
    float* om   = ws;                        // 884736 f
    float* st   = om + 884736;               // 512 f
    float* ps   = st + 512;                  // 16384 f (32 copies x 512)
    u16*   yb   = (u16*)(ps + 16384);        // 8388608 u16 (16.8 MB)
    u16*   wfr  = yb + 8388608;              // 589824 u16
    u16*   wofr = wfr + 589824;              // 73728 u16
    u16*   Xt   = wofr + 73728;              // 8388608 u16 (16.8 MB)

    k_prep<<<2592, 256, 0, stream>>>(weight, w_off, wfr, wofr);
    k_xt<<<512, 256, 0, stream>>>(x, Xt);
    hipMemsetAsync(ps, 0, 16384 * sizeof(float), stream);
    k_offmfma<<<512, 256, 0, stream>>>(Xt, wofr, b_off, om);

    k_sgemm<<<512, 512, 0, stream>>>(Xt, om, wfr, bias, yb, ps);

    k_stats2<<<1, 256, 0, stream>>>(ps, st);
    k_norm<<<(2 * CO * HW / 8 + 255) / 256, 256, 0, stream>>>(yb, st, gamma, beta, out);
}

// Round 17
// 122.340 us; speedup vs baseline: 1.1705x; 1.0086x over previous
//
#include <hip/hip_runtime.h>
#include <hip/hip_fp16.h>
#include <math.h>

#define HW 16384
#define Cc 256
#define CO 256

typedef unsigned short u16;
typedef unsigned int   u32;
typedef __attribute__((ext_vector_type(8))) _Float16 f16x8;
typedef __attribute__((ext_vector_type(4))) float f32x4;

__device__ __forceinline__ u16 f2h(float f) {
    return __half_as_ushort(__float2half(f));     // RNE f32->f16
}

// ---------------- Kernel 1: fused prep (weights frag order + x->Xt + ps zero) ----------------
// blocks [0,512): x -> Xt[b][hw][c] fp16
// blocks [512,3104): weight transposes (main + offset)
// blocks [3104,3168): zero ps
__global__ __launch_bounds__(256) void k_prep(const float* __restrict__ x,
                                              const float* __restrict__ w,
                                              const float* __restrict__ wof,
                                              u16* __restrict__ wfr, u16* __restrict__ wofr,
                                              u16* __restrict__ Xt, float* __restrict__ ps) {
    const int blk = blockIdx.x;
    const int tid = threadIdx.x;
    if (blk < 512) {
        const int hw0 = (blk & 255) * 64;
        const int b   = blk >> 8;
        const int hwl = tid & 63;
        const int cg  = tid >> 6;
        const int hw  = hw0 + hwl;
        const float* xb = x + ((size_t)b << 22);
        u16* dst = Xt + (((size_t)b << 14) + hw) * 256 + cg * 64;
        #pragma unroll
        for (int oct = 0; oct < 8; ++oct) {
            int c0 = cg * 64 + oct * 8;
            u32 pk[4];
            #pragma unroll
            for (int q = 0; q < 4; ++q) {
                float v0 = xb[((size_t)(c0 + 2 * q) << 14) + hw];
                float v1 = xb[((size_t)(c0 + 2 * q + 1) << 14) + hw];
                pk[q] = (u32)f2h(v0) | ((u32)f2h(v1) << 16);
            }
            *(uint4*)(dst + oct * 8) = make_uint4(pk[0], pk[1], pk[2], pk[3]);
        }
    } else if (blk < 3104) {
        int id = (blk - 512) * 256 + tid;
        if (id < 589824) {
            int i    = id & 7;
            int lane = (id >> 3) & 63;
            int fb   = id >> 9;
            int k32  = fb % 72;
            int ot   = fb / 72;
            int o  = ot * 16 + (lane & 15);
            int K  = k32 * 32 + (lane >> 4) * 8 + i;
            int kt = K >> 8;
            int c  = K & 255;
            wfr[id] = f2h(w[((size_t)o * 256 + c) * 9 + kt]);
        } else if (id < 663552) {
            int id2  = id - 589824;
            int i    = id2 & 7;
            int lane = (id2 >> 3) & 63;
            int fb   = id2 >> 9;
            int k32  = fb % 72;
            int mt   = fb / 72;
            int o  = mt * 16 + (lane & 15);
            int K  = k32 * 32 + (lane >> 4) * 8 + i;
            int t  = K >> 8;
            int c  = K & 255;
            float v = (o < 27) ? wof[((size_t)o * 256 + c) * 9 + t] : 0.0f;
            wofr[id2] = f2h(v);
        }
    } else {
        int id3 = (blk - 3104) * 256 + tid;
        if (id3 < 16384) ps[id3] = 0.0f;
    }
}

// ---------------- Kernel 2: offset conv MFMA (fp16), FULL K per block (no atomics) ----------------
__global__ __launch_bounds__(256) void k_offmfma(const u16* __restrict__ Xt,
                                                 const u16* __restrict__ wofr,
                                                 const float* __restrict__ bof,
                                                 float* __restrict__ om) {
    const int tid  = threadIdx.x;
    const int wid  = tid >> 6;
    const int lane = tid & 63;
    const int bid  = blockIdx.x;
    const int wq   = bid & 1;
    const int h    = (bid >> 1) & 127;
    const int b    = bid >> 8;

    const int lr = lane & 15;
    const int lg = lane >> 4;
    const int w  = wq * 64 + wid * 16 + lr;

    f32x4 acc0 = (f32x4)0.0f, acc1 = (f32x4)0.0f;
    const u16* XtB = Xt + (((size_t)b << 14) << 8);

    for (int t = 0; t < 9; ++t) {
        int dh = t / 3 - 1;
        int dw = t % 3 - 1;
        int hh = h + dh;
        int ww = w + dw;
        bool valid = (hh >= 0) && (hh < 128) && (ww >= 0) && (ww < 128);
        int hc = min(max(hh, 0), 127);
        int wc = min(max(ww, 0), 127);
        const u16* xrow = XtB + ((size_t)(hc * 128 + wc) << 8) + lg * 8;
        #pragma unroll
        for (int c32 = 0; c32 < 8; ++c32) {
            int k32 = t * 8 + c32;
            f16x8 bv = *(const f16x8*)(xrow + c32 * 32);
            if (!valid) bv = (f16x8)0;
            f16x8 a0 = *(const f16x8*)(wofr + (((size_t)k32 * 64 + lane) << 3));
            f16x8 a1 = *(const f16x8*)(wofr + ((((size_t)(72 + k32)) * 64 + lane) << 3));
            acc0 = __builtin_amdgcn_mfma_f32_16x16x32_f16(a0, bv, acc0, 0, 0, 0);
            acc1 = __builtin_amdgcn_mfma_f32_16x16x32_f16(a1, bv, acc1, 0, 0, 0);
        }
    }

    float* omb = om + ((size_t)b * 27 << 14) + h * 128 + w;
    #pragma unroll
    for (int j = 0; j < 4; ++j) {
        int o = lg * 4 + j;
        omb[(size_t)o << 14] = acc0[j] + bof[o];
        int o1 = 16 + lg * 4 + j;
        if (o1 < 27) omb[(size_t)o1 << 14] = acc1[j] + bof[o1];
    }
}

// ---------------- Kernel 3: FUSED deform-gather + fp16 MFMA GEMM, 8 waves, K-step 128 ----------------
// r16 structure (64us) with BK 64->128: 18 steps (barriers halved), 32 MFMA per
// step per wave, 8 corner loads in flight per step (load->use distance doubled
// naturally, no extra prefetch buffers). LDS 50KB, still 2 blocks/CU.
// Swizzle: LDS chunk q of row r holds channel-chunk q^(r&15); read inverts.
__global__ __launch_bounds__(512) void k_sgemm(const u16* __restrict__ Xt,
                                               const float* __restrict__ om,
                                               const u16* __restrict__ wfr,
                                               const float* __restrict__ bias,
                                               u16* __restrict__ y,
                                               float* __restrict__ psum) {
    __shared__ int4    soff[9][64];
    __shared__ __half2 swt2[9][64][4];
    __shared__ __align__(16) u16 Blds[2][8192];     // 64 pos x 128 ch, x2 buffers

    const int tid  = threadIdx.x;            // 0..511
    const int wid  = tid >> 6;                // 0..7
    const int lane = tid & 63;
    const int bid  = ((blockIdx.x & 7) << 6) | (blockIdx.x >> 3);  // XCD swizzle
    const int p0   = bid * 64;
    const int b    = p0 >> 14;
    const int hwb  = p0 & 16383;

    // ---- coords: 64 pos x 9 taps ----
    for (int e = tid; e < 576; e += 512) {
        int t = e >> 6, j = e & 63;
        int hw = hwb + j;
        int h = hw >> 7, wc = hw & 127;
        const size_t ob = (size_t)b * 27 * HW;
        float oy = om[ob + (size_t)t * HW + hw];
        float ox = om[ob + (size_t)(9 + t) * HW + hw];
        float mv = om[ob + (size_t)(18 + t) * HW + hw];
        mv = 1.0f / (1.0f + expf(-mv));
        float py = (float)h - 1.0f + (float)(t / 3) + oy;
        float px = (float)wc - 1.0f + (float)(t % 3) + ox;
        float y0f = floorf(py), x0f = floorf(px);
        float wy = py - y0f, wx = px - x0f;
        int iy = (int)y0f, ix = (int)x0f;
        float w4[4] = {(1.0f - wy) * (1.0f - wx), (1.0f - wy) * wx,
                       wy * (1.0f - wx),          wy * wx};
        const int dy[4] = {0, 0, 1, 1};
        const int dx[4] = {0, 1, 0, 1};
        int of[4];
        #pragma unroll
        for (int r = 0; r < 4; ++r) {
            int yy = iy + dy[r], xx = ix + dx[r];
            bool v = (yy >= 0) && (yy <= 127) && (xx >= 0) && (xx <= 127);
            int yc = min(max(yy, 0), 127);
            int xc = min(max(xx, 0), 127);
            of[r] = yc * 128 + xc;
            swt2[t][j][r] = __float2half2_rn(v ? w4[r] * mv : 0.0f);
        }
        soff[t][j] = make_int4(of[0], of[1], of[2], of[3]);
    }
    __syncthreads();

    const int jp  = tid >> 3;                 // pos row 0..63
    const int sw  = jp & 15;
    const int q0  = (tid & 7) << 1;           // this thread's LDS chunk pair
    const int kloc0 = ((q0 ^ sw) << 3);       // channel elem offset, chunk 0
    const int kloc1 = (((q0 | 1) ^ sw) << 3); // channel elem offset, chunk 1
    const u16* XtB  = Xt + (((size_t)b << 14) << 8);

    const int lg = lane >> 4;
    const int lr = lane & 15;

    f32x4 acc[2][4];
    #pragma unroll
    for (int m = 0; m < 2; ++m)
        #pragma unroll
        for (int n = 0; n < 4; ++n) acc[m][n] = (f32x4)0.0f;

    auto gload = [&](int s, uint4* gg) {
        int t = s >> 1;
        int cb = (s & 1) << 7;                // half: 128 elems
        int4 oa = soff[t][jp];
        const u16* pa = XtB + (size_t)oa.x * 256 + cb;
        const u16* pb = XtB + (size_t)oa.y * 256 + cb;
        const u16* pc = XtB + (size_t)oa.z * 256 + cb;
        const u16* pd = XtB + (size_t)oa.w * 256 + cb;
        gg[0] = *(const uint4*)(pa + kloc0);
        gg[1] = *(const uint4*)(pb + kloc0);
        gg[2] = *(const uint4*)(pc + kloc0);
        gg[3] = *(const uint4*)(pd + kloc0);
        gg[4] = *(const uint4*)(pa + kloc1);
        gg[5] = *(const uint4*)(pb + kloc1);
        gg[6] = *(const uint4*)(pc + kloc1);
        gg[7] = *(const uint4*)(pd + kloc1);
    };
    auto gcomb = [&](int s, const uint4* gg, int buf) {
        int t = s >> 1;
        __half2 w0 = swt2[t][jp][0];
        __half2 w1 = swt2[t][jp][1];
        __half2 w2 = swt2[t][jp][2];
        __half2 w3 = swt2[t][jp][3];
        const __half2* hh = (const __half2*)gg;   // [corner*4+q] chunk0 at 0..15, chunk1 at 16..31
        u32 oA[4], oB[4];
        #pragma unroll
        for (int q = 0; q < 4; ++q) {
            __half2 o = __hmul2(hh[q], w0);
            o = __hfma2(hh[4 + q],  w1, o);
            o = __hfma2(hh[8 + q],  w2, o);
            o = __hfma2(hh[12 + q], w3, o);
            oA[q] = *(const u32*)&o;
            __half2 o2 = __hmul2(hh[16 + q], w0);
            o2 = __hfma2(hh[20 + q], w1, o2);
            o2 = __hfma2(hh[24 + q], w2, o2);
            o2 = __hfma2(hh[28 + q], w3, o2);
            oB[q] = *(const u32*)&o2;
        }
        char* dst = (char*)&Blds[buf][0] + tid * 32;
        *(uint4*)dst        = make_uint4(oA[0], oA[1], oA[2], oA[3]);
        *(uint4*)(dst + 16) = make_uint4(oB[0], oB[1], oB[2], oB[3]);
    };
    auto aload = [&](int k32g, f16x8 dst2[4][2]) {
        #pragma unroll
        for (int kk = 0; kk < 4; ++kk)
            #pragma unroll
            for (int m = 0; m < 2; ++m)
                dst2[kk][m] = *(const f16x8*)(wfr +
                    ((size_t)((wid * 2 + m) * 72 + k32g + kk) << 9) + (size_t)lane * 8);
    };

    f16x8 af[4][2];
    // ---- prologue: step 0 ----
    {
        uint4 g[8];
        gload(0, g);
        aload(0, af);
        gcomb(0, g, 0);
    }
    __syncthreads();

    int cur = 0;
    for (int s = 0; s < 18; ++s) {
        const int nxt = cur ^ 1;
        uint4 gn[8];
        f16x8 afn[4][2];
        if (s < 17) {
            gload(s + 1, gn);
            aload(4 * (s + 1), afn);
        }

        const char* bb2 = (const char*)&Blds[cur][0];
        #pragma unroll
        for (int kk = 0; kk < 4; ++kk) {
            f16x8 bfv[4];
            #pragma unroll
            for (int n = 0; n < 4; ++n) {
                int row  = n * 16 + lr;
                int boff = row * 256 + ((((kk * 4 + lg) ^ (row & 15))) << 4);
                bfv[n] = *(const f16x8*)(bb2 + boff);
            }
            #pragma unroll
            for (int m = 0; m < 2; ++m)
                #pragma unroll
                for (int n = 0; n < 4; ++n)
                    acc[m][n] = __builtin_amdgcn_mfma_f32_16x16x32_f16(af[kk][m], bfv[n], acc[m][n], 0, 0, 0);
        }

        if (s < 17) {
            gcomb(s + 1, gn, nxt);
            #pragma unroll
            for (int kk = 0; kk < 4; ++kk)
                #pragma unroll
                for (int m = 0; m < 2; ++m)
                    af[kk][m] = afn[kk][m];
        }
        __syncthreads();
        cur = nxt;
    }

    // ---- epilogue: bias + write y (fp16) + fused BN partial sums (spread 32-way) ----
    const int hw0  = hwb + lr;
    const int slot = (bid & 31) << 9;          // 32 psum copies of 512 floats
    #pragma unroll
    for (int m = 0; m < 2; ++m) {
        #pragma unroll
        for (int jj = 0; jj < 4; ++jj) {
            int o = wid * 32 + m * 16 + lg * 4 + jj;
            float bv = bias[o];
            u16* ya = y + ((size_t)b * 256 + o) * HW + hw0;
            float ssum = 0.0f, ssq = 0.0f;
            #pragma unroll
            for (int n = 0; n < 4; ++n) {
                float v = acc[m][n][jj] + bv;
                ya[n * 16] = f2h(v);
                ssum += v;
                ssq  += v * v;
            }
            #pragma unroll
            for (int d = 1; d < 16; d <<= 1) {
                ssum += __shfl_xor(ssum, d);
                ssq  += __shfl_xor(ssq, d);
            }
            if (lr == 0) {
                atomicAdd(&psum[slot + o], ssum);
                atomicAdd(&psum[slot + 256 + o], ssq);
            }
        }
    }
}

// ---------------- Kernel 4: psum (32 copies) -> mu / rsig ----------------
__global__ void k_stats2(const float* __restrict__ psum, float* __restrict__ st) {
    int o = threadIdx.x;
    float s = 0.0f, q = 0.0f;
    #pragma unroll 8
    for (int r = 0; r < 32; ++r) {
        s += psum[(r << 9) + o];
        q += psum[(r << 9) + 256 + o];
    }
    float mu  = s / 32768.0f;
    float var = q / 32768.0f - mu * mu;
    st[o]       = mu;
    st[256 + o] = rsqrtf(var + 1e-5f);
}

// ---------------- Kernel 5: normalize + relu (fp16 y input) ----------------
__global__ void k_norm(const u16* __restrict__ y, const float* __restrict__ stats,
                       const float* __restrict__ gamma, const float* __restrict__ beta,
                       float* __restrict__ out) {
    int i8 = blockIdx.x * 256 + threadIdx.x;       // uint4 index = 8 fp16 elems
    if (i8 >= (2 * CO * HW) / 8) return;
    int o = ((i8 * 8) >> 14) & 255;
    float g  = gamma[o] * stats[256 + o];
    float bt = beta[o] - stats[o] * g;
    uint4 v = ((const uint4*)y)[i8];
    const __half2* h2 = (const __half2*)&v;
    float4 r0, r1;
    float2 f0 = __half22float2(h2[0]);
    float2 f1 = __half22float2(h2[1]);
    float2 f2 = __half22float2(h2[2]);
    float2 f3 = __half22float2(h2[3]);
    r0.x = fmaxf(fmaf(f0.x, g, bt), 0.0f);
    r0.y = fmaxf(fmaf(f0.y, g, bt), 0.0f);
    r0.z = fmaxf(fmaf(f1.x, g, bt), 0.0f);
    r0.w = fmaxf(fmaf(f1.y, g, bt), 0.0f);
    r1.x = fmaxf(fmaf(f2.x, g, bt), 0.0f);
    r1.y = fmaxf(fmaf(f2.y, g, bt), 0.0f);
    r1.z = fmaxf(fmaf(f3.x, g, bt), 0.0f);
    r1.w = fmaxf(fmaf(f3.y, g, bt), 0.0f);
    float4* op = (float4*)(out + (size_t)i8 * 8);
    op[0] = r0;
    op[1] = r1;
}

extern "C" void kernel_launch(void* const* d_in, const int* in_sizes, int n_in,
                              void* d_out, int out_size, void* d_ws, size_t ws_size,
                              hipStream_t stream) {
    const float* x      = (const float*)d_in[0];
    const float* w_off  = (const float*)d_in[1];
    const float* b_off  = (const float*)d_in[2];
    const float* weight = (const float*)d_in[3];
    const float* bias   = (const float*)d_in[4];
    const float* gamma  = (const float*)d_in[5];
    const float* beta   = (const float*)d_in[6];
    float* out = (float*)d_out;

    float* ws   = (float*)d_ws;
    float* om   = ws;                        // 884736 f
    float* st   = om + 884736;               // 512 f
    float* ps   = st + 512;                  // 16384 f (32 copies x 512)
    u16*   yb   = (u16*)(ps + 16384);        // 8388608 u16 (16.8 MB)
    u16*   wfr  = yb + 8388608;              // 589824 u16
    u16*   wofr = wfr + 589824;              // 73728 u16
    u16*   Xt   = wofr + 73728;              // 8388608 u16 (16.8 MB)

    k_prep<<<3168, 256, 0, stream>>>(x, weight, w_off, wfr, wofr, Xt, ps);
    k_offmfma<<<512, 256, 0, stream>>>(Xt, wofr, b_off, om);

    k_sgemm<<<512, 512, 0, stream>>>(Xt, om, wfr, bias, yb, ps);

    k_stats2<<<1, 256, 0, stream>>>(ps, st);
    k_norm<<<(2 * CO * HW / 8 + 255) / 256, 256, 0, stream>>>(yb, st, gamma, beta, out);
}

// Round 18
// 118.147 us; speedup vs baseline: 1.2121x; 1.0355x over previous
//
#include <hip/hip_runtime.h>
#include <hip/hip_fp16.h>
#include <math.h>

#define HW 16384
#define Cc 256
#define CO 256

typedef unsigned short u16;
typedef unsigned int   u32;
typedef __attribute__((ext_vector_type(8))) _Float16 f16x8;
typedef __attribute__((ext_vector_type(4))) float f32x4;

__device__ __forceinline__ u16 f2h(float f) {
    return __half_as_ushort(__float2half(f));     // RNE f32->f16
}

// ---------------- Kernel 1: fused prep (x->Xt + weights frag order + ps zero) ----------------
// blocks [0,512): x -> Xt[b][hw][c] fp16
// blocks [512,3104): weight transposes (main + offset)
// blocks [3104,3168): zero ps
__global__ __launch_bounds__(256) void k_prep(const float* __restrict__ x,
                                              const float* __restrict__ w,
                                              const float* __restrict__ wof,
                                              u16* __restrict__ wfr, u16* __restrict__ wofr,
                                              u16* __restrict__ Xt, float* __restrict__ ps) {
    const int blk = blockIdx.x;
    const int tid = threadIdx.x;
    if (blk < 512) {
        const int hw0 = (blk & 255) * 64;
        const int b   = blk >> 8;
        const int hwl = tid & 63;
        const int cg  = tid >> 6;
        const int hw  = hw0 + hwl;
        const float* xb = x + ((size_t)b << 22);
        u16* dst = Xt + (((size_t)b << 14) + hw) * 256 + cg * 64;
        #pragma unroll
        for (int oct = 0; oct < 8; ++oct) {
            int c0 = cg * 64 + oct * 8;
            u32 pk[4];
            #pragma unroll
            for (int q = 0; q < 4; ++q) {
                float v0 = xb[((size_t)(c0 + 2 * q) << 14) + hw];
                float v1 = xb[((size_t)(c0 + 2 * q + 1) << 14) + hw];
                pk[q] = (u32)f2h(v0) | ((u32)f2h(v1) << 16);
            }
            *(uint4*)(dst + oct * 8) = make_uint4(pk[0], pk[1], pk[2], pk[3]);
        }
    } else if (blk < 3104) {
        int id = (blk - 512) * 256 + tid;
        if (id < 589824) {
            int i    = id & 7;
            int lane = (id >> 3) & 63;
            int fb   = id >> 9;
            int k32  = fb % 72;
            int ot   = fb / 72;
            int o  = ot * 16 + (lane & 15);
            int K  = k32 * 32 + (lane >> 4) * 8 + i;
            int kt = K >> 8;
            int c  = K & 255;
            wfr[id] = f2h(w[((size_t)o * 256 + c) * 9 + kt]);
        } else if (id < 663552) {
            int id2  = id - 589824;
            int i    = id2 & 7;
            int lane = (id2 >> 3) & 63;
            int fb   = id2 >> 9;
            int k32  = fb % 72;
            int mt   = fb / 72;
            int o  = mt * 16 + (lane & 15);
            int K  = k32 * 32 + (lane >> 4) * 8 + i;
            int t  = K >> 8;
            int c  = K & 255;
            float v = (o < 27) ? wof[((size_t)o * 256 + c) * 9 + t] : 0.0f;
            wofr[id2] = f2h(v);
        }
    } else {
        int id3 = (blk - 3104) * 256 + tid;
        if (id3 < 16384) ps[id3] = 0.0f;
    }
}

// ---------------- Kernel 2: offset conv MFMA (fp16), FULL K per block (no atomics) ----------------
__global__ __launch_bounds__(256) void k_offmfma(const u16* __restrict__ Xt,
                                                 const u16* __restrict__ wofr,
                                                 const float* __restrict__ bof,
                                                 float* __restrict__ om) {
    const int tid  = threadIdx.x;
    const int wid  = tid >> 6;
    const int lane = tid & 63;
    const int bid  = blockIdx.x;
    const int wq   = bid & 1;
    const int h    = (bid >> 1) & 127;
    const int b    = bid >> 8;

    const int lr = lane & 15;
    const int lg = lane >> 4;
    const int w  = wq * 64 + wid * 16 + lr;

    f32x4 acc0 = (f32x4)0.0f, acc1 = (f32x4)0.0f;
    const u16* XtB = Xt + (((size_t)b << 14) << 8);

    for (int t = 0; t < 9; ++t) {
        int dh = t / 3 - 1;
        int dw = t % 3 - 1;
        int hh = h + dh;
        int ww = w + dw;
        bool valid = (hh >= 0) && (hh < 128) && (ww >= 0) && (ww < 128);
        int hc = min(max(hh, 0), 127);
        int wc = min(max(ww, 0), 127);
        const u16* xrow = XtB + ((size_t)(hc * 128 + wc) << 8) + lg * 8;
        #pragma unroll
        for (int c32 = 0; c32 < 8; ++c32) {
            int k32 = t * 8 + c32;
            f16x8 bv = *(const f16x8*)(xrow + c32 * 32);
            if (!valid) bv = (f16x8)0;
            f16x8 a0 = *(const f16x8*)(wofr + (((size_t)k32 * 64 + lane) << 3));
            f16x8 a1 = *(const f16x8*)(wofr + ((((size_t)(72 + k32)) * 64 + lane) << 3));
            acc0 = __builtin_amdgcn_mfma_f32_16x16x32_f16(a0, bv, acc0, 0, 0, 0);
            acc1 = __builtin_amdgcn_mfma_f32_16x16x32_f16(a1, bv, acc1, 0, 0, 0);
        }
    }

    float* omb = om + ((size_t)b * 27 << 14) + h * 128 + w;
    #pragma unroll
    for (int j = 0; j < 4; ++j) {
        int o = lg * 4 + j;
        omb[(size_t)o << 14] = acc0[j] + bof[o];
        int o1 = 16 + lg * 4 + j;
        if (o1 < 27) omb[(size_t)o1 << 14] = acc1[j] + bof[o1];
    }
}

// ---------------- Kernel 3: FUSED deform-gather + fp16 MFMA GEMM, 8 waves ----------------
// EXACT r16 main loop (64us): grid 512 (XCD-swizzled), block 512 = 8 waves,
// M=32/wave, N=64 pos, K=2304, 36 steps, single-step prefetch, linear LDS
// writes (0 bank conflicts), fp16 y epilogue, spread-32 psum.
__global__ __launch_bounds__(512) void k_sgemm(const u16* __restrict__ Xt,
                                               const float* __restrict__ om,
                                               const u16* __restrict__ wfr,
                                               const float* __restrict__ bias,
                                               u16* __restrict__ y,
                                               float* __restrict__ psum) {
    __shared__ int4    soff[9][64];
    __shared__ __half2 swt2[9][64][4];
    __shared__ __align__(16) u16 Blds[2][4096];

    const int tid  = threadIdx.x;            // 0..511
    const int wid  = tid >> 6;                // 0..7
    const int lane = tid & 63;
    const int bid  = ((blockIdx.x & 7) << 6) | (blockIdx.x >> 3);  // XCD swizzle
    const int p0   = bid * 64;
    const int b    = p0 >> 14;
    const int hwb  = p0 & 16383;

    // ---- coords: 64 pos x 9 taps ----
    for (int e = tid; e < 576; e += 512) {
        int t = e >> 6, j = e & 63;
        int hw = hwb + j;
        int h = hw >> 7, wc = hw & 127;
        const size_t ob = (size_t)b * 27 * HW;
        float oy = om[ob + (size_t)t * HW + hw];
        float ox = om[ob + (size_t)(9 + t) * HW + hw];
        float mv = om[ob + (size_t)(18 + t) * HW + hw];
        mv = 1.0f / (1.0f + expf(-mv));
        float py = (float)h - 1.0f + (float)(t / 3) + oy;
        float px = (float)wc - 1.0f + (float)(t % 3) + ox;
        float y0f = floorf(py), x0f = floorf(px);
        float wy = py - y0f, wx = px - x0f;
        int iy = (int)y0f, ix = (int)x0f;
        float w4[4] = {(1.0f - wy) * (1.0f - wx), (1.0f - wy) * wx,
                       wy * (1.0f - wx),          wy * wx};
        const int dy[4] = {0, 0, 1, 1};
        const int dx[4] = {0, 1, 0, 1};
        int of[4];
        #pragma unroll
        for (int r = 0; r < 4; ++r) {
            int yy = iy + dy[r], xx = ix + dx[r];
            bool v = (yy >= 0) && (yy <= 127) && (xx >= 0) && (xx <= 127);
            int yc = min(max(yy, 0), 127);
            int xc = min(max(xx, 0), 127);
            of[r] = yc * 128 + xc;
            swt2[t][j][r] = __float2half2_rn(v ? w4[r] * mv : 0.0f);
        }
        soff[t][j] = make_int4(of[0], of[1], of[2], of[3]);
    }
    __syncthreads();

    const int jp    = tid >> 3;                        // pos row 0..63
    const int kloc8 = (((tid & 7) ^ (jp & 7)) << 3);   // pre-swizzled 8-ch k-slice
    const u16* XtB  = Xt + (((size_t)b << 14) << 8);

    const int lg = lane >> 4;
    const int lr = lane & 15;

    f32x4 acc[2][4];
    #pragma unroll
    for (int m = 0; m < 2; ++m)
        #pragma unroll
        for (int n = 0; n < 4; ++n) acc[m][n] = (f32x4)0.0f;

    auto gload = [&](int s, uint4* gg) {
        int t = s >> 2;
        int c = ((s & 3) << 6) + kloc8;
        int4 oa = soff[t][jp];
        gg[0] = *(const uint4*)(XtB + (size_t)oa.x * 256 + c);
        gg[1] = *(const uint4*)(XtB + (size_t)oa.y * 256 + c);
        gg[2] = *(const uint4*)(XtB + (size_t)oa.z * 256 + c);
        gg[3] = *(const uint4*)(XtB + (size_t)oa.w * 256 + c);
    };
    auto gcomb = [&](int s, const uint4* gg, int buf) {
        int t = s >> 2;
        __half2 w0 = swt2[t][jp][0];
        __half2 w1 = swt2[t][jp][1];
        __half2 w2 = swt2[t][jp][2];
        __half2 w3 = swt2[t][jp][3];
        const __half2* c0 = (const __half2*)&gg[0];
        const __half2* c1 = (const __half2*)&gg[1];
        const __half2* c2 = (const __half2*)&gg[2];
        const __half2* c3 = (const __half2*)&gg[3];
        u32 o4[4];
        #pragma unroll
        for (int q = 0; q < 4; ++q) {
            __half2 o = __hmul2(c0[q], w0);
            o = __hfma2(c1[q], w1, o);
            o = __hfma2(c2[q], w2, o);
            o = __hfma2(c3[q], w3, o);
            o4[q] = *(const u32*)&o;
        }
        *(uint4*)((char*)&Blds[buf][0] + tid * 16) = make_uint4(o4[0], o4[1], o4[2], o4[3]);
    };
    auto aload = [&](int k32g, f16x8 dst2[2][2]) {
        #pragma unroll
        for (int kk = 0; kk < 2; ++kk)
            #pragma unroll
            for (int m = 0; m < 2; ++m)
                dst2[kk][m] = *(const f16x8*)(wfr +
                    ((size_t)((wid * 2 + m) * 72 + k32g + kk) << 9) + (size_t)lane * 8);
    };

    f16x8 af[2][2];
    // ---- prologue: step 0 ----
    {
        uint4 g[4];
        gload(0, g);
        aload(0, af);
        gcomb(0, g, 0);
    }
    __syncthreads();

    int cur = 0;
    for (int s = 0; s < 36; ++s) {
        const int nxt = cur ^ 1;
        uint4 gn[4];
        f16x8 afn[2][2];
        if (s < 35) {
            gload(s + 1, gn);
            aload(2 * (s + 1), afn);
        }

        const char* bb2 = (const char*)&Blds[cur][0];
        #pragma unroll
        for (int kk = 0; kk < 2; ++kk) {
            f16x8 bfv[4];
            #pragma unroll
            for (int n = 0; n < 4; ++n) {
                int row  = n * 16 + lr;
                int boff = row * 128 + ((kk * 64 + lg * 16) ^ ((row & 7) << 4));
                bfv[n] = *(const f16x8*)(bb2 + boff);
            }
            #pragma unroll
            for (int m = 0; m < 2; ++m)
                #pragma unroll
                for (int n = 0; n < 4; ++n)
                    acc[m][n] = __builtin_amdgcn_mfma_f32_16x16x32_f16(af[kk][m], bfv[n], acc[m][n], 0, 0, 0);
        }

        if (s < 35) {
            gcomb(s + 1, gn, nxt);
            #pragma unroll
            for (int kk = 0; kk < 2; ++kk)
                #pragma unroll
                for (int m = 0; m < 2; ++m)
                    af[kk][m] = afn[kk][m];
        }
        __syncthreads();
        cur = nxt;
    }

    // ---- epilogue: bias + write y (fp16) + fused BN partial sums (spread 32-way) ----
    const int hw0  = hwb + lr;
    const int slot = (bid & 31) << 9;          // 32 psum copies of 512 floats
    #pragma unroll
    for (int m = 0; m < 2; ++m) {
        #pragma unroll
        for (int jj = 0; jj < 4; ++jj) {
            int o = wid * 32 + m * 16 + lg * 4 + jj;
            float bv = bias[o];
            u16* ya = y + ((size_t)b * 256 + o) * HW + hw0;
            float ssum = 0.0f, ssq = 0.0f;
            #pragma unroll
            for (int n = 0; n < 4; ++n) {
                float v = acc[m][n][jj] + bv;
                ya[n * 16] = f2h(v);
                ssum += v;
                ssq  += v * v;
            }
            #pragma unroll
            for (int d = 1; d < 16; d <<= 1) {
                ssum += __shfl_xor(ssum, d);
                ssq  += __shfl_xor(ssq, d);
            }
            if (lr == 0) {
                atomicAdd(&psum[slot + o], ssum);
                atomicAdd(&psum[slot + 256 + o], ssq);
            }
        }
    }
}

// ---------------- Kernel 4: psum (32 copies) -> mu / rsig ----------------
__global__ void k_stats2(const float* __restrict__ psum, float* __restrict__ st) {
    int o = threadIdx.x;
    float s = 0.0f, q = 0.0f;
    #pragma unroll 8
    for (int r = 0; r < 32; ++r) {
        s += psum[(r << 9) + o];
        q += psum[(r << 9) + 256 + o];
    }
    float mu  = s / 32768.0f;
    float var = q / 32768.0f - mu * mu;
    st[o]       = mu;
    st[256 + o] = rsqrtf(var + 1e-5f);
}

// ---------------- Kernel 5: normalize + relu (fp16 y input) ----------------
__global__ void k_norm(const u16* __restrict__ y, const float* __restrict__ stats,
                       const float* __restrict__ gamma, const float* __restrict__ beta,
                       float* __restrict__ out) {
    int i8 = blockIdx.x * 256 + threadIdx.x;       // uint4 index = 8 fp16 elems
    if (i8 >= (2 * CO * HW) / 8) return;
    int o = ((i8 * 8) >> 14) & 255;
    float g  = gamma[o] * stats[256 + o];
    float bt = beta[o] - stats[o] * g;
    uint4 v = ((const uint4*)y)[i8];
    const __half2* h2 = (const __half2*)&v;
    float4 r0, r1;
    float2 f0 = __half22float2(h2[0]);
    float2 f1 = __half22float2(h2[1]);
    float2 f2 = __half22float2(h2[2]);
    float2 f3 = __half22float2(h2[3]);
    r0.x = fmaxf(fmaf(f0.x, g, bt), 0.0f);
    r0.y = fmaxf(fmaf(f0.y, g, bt), 0.0f);
    r0.z = fmaxf(fmaf(f1.x, g, bt), 0.0f);
    r0.w = fmaxf(fmaf(f1.y, g, bt), 0.0f);
    r1.x = fmaxf(fmaf(f2.x, g, bt), 0.0f);
    r1.y = fmaxf(fmaf(f2.y, g, bt), 0.0f);
    r1.z = fmaxf(fmaf(f3.x, g, bt), 0.0f);
    r1.w = fmaxf(fmaf(f3.y, g, bt), 0.0f);
    float4* op = (float4*)(out + (size_t)i8 * 8);
    op[0] = r0;
    op[1] = r1;
}

extern "C" void kernel_launch(void* const* d_in, const int* in_sizes, int n_in,
                              void* d_out, int out_size, void* d_ws, size_t ws_size,
                              hipStream_t stream) {
    const float* x      = (const float*)d_in[0];
    const float* w_off  = (const float*)d_in[1];
    const float* b_off  = (const float*)d_in[2];
    const float* weight = (const float*)d_in[3];
    const float* bias   = (const float*)d_in[4];
    const float* gamma  = (const float*)d_in[5];
    const float* beta   = (const float*)d_in[6];
    float* out = (float*)d_out;

    float* ws   = (float*)d_ws;
    float* om   = ws;                        // 884736 f
    float* st   = om + 884736;               // 512 f
    float* ps   = st + 512;                  // 16384 f (32 copies x 512)
    u16*   yb   = (u16*)(ps + 16384);        // 8388608 u16 (16.8 MB)
    u16*   wfr  = yb + 8388608;              // 589824 u16
    u16*   wofr = wfr + 589824;              // 73728 u16
    u16*   Xt   = wofr + 73728;              // 8388608 u16 (16.8 MB)

    k_prep<<<3168, 256, 0, stream>>>(x, weight, w_off, wfr, wofr, Xt, ps);
    k_offmfma<<<512, 256, 0, stream>>>(Xt, wofr, b_off, om);

    k_sgemm<<<512, 512, 0, stream>>>(Xt, om, wfr, bias, yb, ps);

    k_stats2<<<1, 256, 0, stream>>>(ps, st);
    k_norm<<<(2 * CO * HW / 8 + 255) / 256, 256, 0, stream>>>(yb, st, gamma, beta, out);
}